// Round 13
// baseline (486.602 us; speedup 1.0000x reference)
//
#include <hip/hip_runtime.h>
#include <math.h>

#define NODES 100000
#define EDGES 1600000
#define HF 128
#define NC 20
#define CAPN 64                         // LDS edge slots/node (P(deg>=64)~2e-13 over graph)
#define BSHIFT 6
#define BNODES 64                       // nodes per bucket == nodes per layer block (1:1 grid)
#define NBK ((NODES + BNODES - 1) / BNODES)   // 1563 buckets = layer grid
#define CAPB 1280                       // bucket edge capacity (mean 1024, sd 32, +8 sigma)
#define EPB 4096                        // edges per partition block
#define NPB ((EDGES + EPB - 1) / EPB)   // 391 partition blocks
#define XB ((NODES * HF / 8 + 255) / 256)

typedef __attribute__((ext_vector_type(8))) short bf16x8;
typedef __attribute__((ext_vector_type(4))) float f32x4;
typedef __attribute__((ext_vector_type(2))) float f32x2;

__device__ __forceinline__ ushort f2b(float f) {
    uint u = __float_as_uint(f);
    uint r = (u + 0x7FFFu + ((u >> 16) & 1u)) >> 16;
    return (ushort)r;
}
__device__ __forceinline__ uchar f2q(float f) {
    return (uchar)(__builtin_amdgcn_cvt_pk_fp8_f32(f, f, 0, false) & 0xFF);
}

// ---- merged partition + converters (one dispatch; bcur pre-zeroed) ----
// Partition r13: SINGLE-PASS global-atomic append. The 3-phase LDS
// histogram+reserve+scatter structure netted ~0 across r10-r12 — its cost
// was the serial phase structure, not TLP or write-amp. Slot alloc is one
// global atomicAdd per edge on 1563 independent counters (~1K adds/word,
// memory-side L2, parallel across counters); ebuf (8MB) stays L2-resident
// between prep and layer 1. r6's 134.8MB write-amp disaster was scattered
// 256B NODE-rows, not bucket appends — does not apply here. Zero LDS,
// zero syncthreads in the partition path. Partition blocks FIRST
// (latency hides under ~6600 converter blocks, r2/r4).
// Entry packing: loc(dst&63)<<17 | src (src < 2^17).
__global__ void prep_kernel(const float* __restrict__ x, ushort* __restrict__ xb,
                            uchar* __restrict__ xq,
                            const float* __restrict__ a, const float* __restrict__ b,
                            const float* __restrict__ c, const float* __restrict__ d,
                            const float* __restrict__ e, const float* __restrict__ wm2,
                            ushort* __restrict__ wb,
                            const int* __restrict__ src, const int* __restrict__ dst,
                            int* __restrict__ bcur, uint* __restrict__ ebufp,
                            int n8, int E) {
    int blk = blockIdx.x;
    int t = threadIdx.x;
    if (blk < NPB) {
        // ---- single-pass bucket append (int4 reads, global-atomic slots) ----
        int base = blk * EPB;
        const int4* d4 = (const int4*)(dst + base);   // E%4==0, base%4==0
        const int4* s4 = (const int4*)(src + base);
#pragma unroll
        for (int it = 0; it < EPB / 1024; ++it) {
            int i4 = it * 256 + t;
            if (base + i4 * 4 < E) {
                int4 dv = d4[i4];
                int4 sv = s4[i4];
                const int dd[4] = {dv.x, dv.y, dv.z, dv.w};
                const int ss[4] = {sv.x, sv.y, sv.z, sv.w};
#pragma unroll
                for (int k = 0; k < 4; ++k) {
                    int bb = dd[k] >> BSHIFT;
                    int pos = bb * CAPB + atomicAdd(&bcur[bb], 1);
                    if (pos < (bb + 1) * CAPB)        // fail-safe (8-sigma)
                        ebufp[pos] = ((uint)(dd[k] & (BNODES - 1)) << 17) | (uint)ss[k];
                }
            }
        }
    } else if (blk < NPB + XB) {
        // ---- x -> bf16 + fp8 ----
        int i = (blk - NPB) * 256 + t;
        if (i >= n8) return;
        const float4* p = (const float4*)x + (size_t)i * 2;
        float4 va = p[0], vb = p[1];
        uint4 o;
        o.x = (uint)f2b(va.x) | ((uint)f2b(va.y) << 16);
        o.y = (uint)f2b(va.z) | ((uint)f2b(va.w) << 16);
        o.z = (uint)f2b(vb.x) | ((uint)f2b(vb.y) << 16);
        o.w = (uint)f2b(vb.z) | ((uint)f2b(vb.w) << 16);
        ((uint4*)xb)[i] = o;
        uint2 q;
        q.x = __builtin_amdgcn_cvt_pk_fp8_f32(va.x, va.y, 0, false);
        q.x = __builtin_amdgcn_cvt_pk_fp8_f32(va.z, va.w, q.x, true);
        q.y = __builtin_amdgcn_cvt_pk_fp8_f32(vb.x, vb.y, 0, false);
        q.y = __builtin_amdgcn_cvt_pk_fp8_f32(vb.z, vb.w, q.y, true);
        ((uint2*)xq)[i] = q;
    } else {
        // ---- weights -> bf16 ----
        int i = (blk - NPB - XB) * 256 + t;
        if (i < 81920) {
            const float* srcs[5] = {a, b, c, d, e};
            wb[i] = f2b(srcs[i >> 14][i & 16383]);
        } else if (i < 86016) {
            int j = i - 81920;
            wb[i] = ((j >> 7) < NC) ? f2b(wm2[j]) : (ushort)0;
        }
    }
}

// ---- fused SAGE layer: out = relu(bias + mean_agg(Xq)@Wl^T + X@Wr^T) ----
// Phase 0: read THIS block's bucket segment (~1024 packed entries, 4KB
//   contiguous, L2-resident) and slot-scatter into sidx via 64 LDS counters —
//   the CSR build, fused (r11: FETCH 101.5->91.2MB). Offsets pre-scaled <<7.
// Phase 1: W=4 exec-masked gather (known-good). Measured dead ends: W=8
//   branchy (occ 20%), depth-2 pipeline (compiler sinks it), branchless
//   clamp-W8 (+dup loads), f32 root (2x root bytes), NT hints, shared zero
//   row. Gather sits at compulsory FETCH floor (8 XCD x working set);
//   remaining ~86us is request latency — frozen.
// Phase 2: 8 waves MFMA dual linear.
// FUSE (layer 2): in-block MLP hidden + head GEMMs through the dead gather
//   tile -> no mlp dispatch, no h2 round-trip (WRITE 37.6 -> 7.8MB).
template<bool EMITQ, bool FUSE>
__global__ __launch_bounds__(512)
void fused_sage_layer(const uchar* __restrict__ Xq, const ushort* __restrict__ X,
                      const uint* __restrict__ ebufp, const int* __restrict__ bcur,
                      const ushort* __restrict__ Wl, const ushort* __restrict__ Wr,
                      const float* __restrict__ bias, ushort* __restrict__ out,
                      uchar* __restrict__ outq,
                      const ushort* __restrict__ Wm1b, const ushort* __restrict__ Wm2b,
                      const float* __restrict__ bm1, const float* __restrict__ bm2,
                      float* __restrict__ fout, int n) {
    __shared__ ushort sh[64][136];     // 17408 B (gather tile; h/hid tile in FUSE)
    __shared__ int sidx[64 * CAPN];    // 16384 B (byte offsets, pre-scaled)
    __shared__ int lcnt[64];
    int row0b = blockIdx.x * 64;
    int t = threadIdx.x;

    // ---- phase 0: in-block CSR build from bucket segment ----
    if (t < 64) lcnt[t] = 0;
    __syncthreads();
    int cb = min(bcur[blockIdx.x], CAPB);
    const uint* ep = ebufp + (size_t)blockIdx.x * CAPB;
    for (int i = t; i < cb; i += 512) {
        uint e = ep[i];
        int loc = (int)(e >> 17);
        int slot = atomicAdd(&lcnt[loc], 1);
        if (slot < CAPN)                  // fail-safe (P ~ 2e-13)
            sidx[loc * CAPN + slot] = (int)((e & 0x1FFFFu) << 7);
    }
    __syncthreads();

    // ---- phase 1: fp8 gather (W=4 exec-masked) ----
    {
        int grp = t >> 5;              // 0..15: node group
        int sub = t & 31;
        int sel = sub >> 3;            // 0..3: edge interleave
        int cg = sub & 7;              // col-group: 16 fp8 cols = 16 B
        const uchar* xc = Xq + cg * 16;
#pragma unroll
        for (int batch = 0; batch < 4; ++batch) {
            int nloc = batch * 16 + grp;
            int node = row0b + nloc;
            int len = min(lcnt[nloc], CAPN);
            int sbase = nloc * CAPN;
            f32x2 acc2[8];
#pragma unroll
            for (int i = 0; i < 8; ++i) acc2[i] = f32x2{0.f, 0.f};
            for (int e = 0; e < len; e += 16) {
                uint4 v[4];
#pragma unroll
                for (int w = 0; w < 4; ++w) {
                    int ee = e + 4 * w + sel;
                    int off = sidx[sbase + ee];       // in-window; garbage if masked
                    uint4 vv = {0u, 0u, 0u, 0u};
                    if (ee < len) vv = *(const uint4*)(xc + (size_t)(uint)off);
                    v[w] = vv;                        // fp8 0x00 -> +0.0f
                }
#pragma unroll
                for (int w = 0; w < 4; ++w) {
                    const uint* pp = (const uint*)&v[w];
#pragma unroll
                    for (int i = 0; i < 4; ++i) {
                        acc2[2 * i]     += __builtin_amdgcn_cvt_pk_f32_fp8(pp[i], false);
                        acc2[2 * i + 1] += __builtin_amdgcn_cvt_pk_f32_fp8(pp[i], true);
                    }
                }
            }
#pragma unroll
            for (int i = 0; i < 8; ++i) {
                acc2[i].x += __shfl_xor(acc2[i].x, 8);
                acc2[i].x += __shfl_xor(acc2[i].x, 16);
                acc2[i].y += __shfl_xor(acc2[i].y, 8);
                acc2[i].y += __shfl_xor(acc2[i].y, 16);
            }
            if (sel == 0 && node < n) {
                float invd = 1.0f / fmaxf((float)len, 1.0f);
                uint4 o0, o1;
                uint* p0 = (uint*)&o0;
                uint* p1 = (uint*)&o1;
#pragma unroll
                for (int i = 0; i < 4; ++i) {
                    p0[i] = (uint)f2b(acc2[i].x * invd) | ((uint)f2b(acc2[i].y * invd) << 16);
                    p1[i] = (uint)f2b(acc2[4 + i].x * invd) | ((uint)f2b(acc2[4 + i].y * invd) << 16);
                }
                *(uint4*)(&sh[nloc][cg * 16]) = o0;
                *(uint4*)(&sh[nloc][cg * 16 + 8]) = o1;
            }
        }
    }
    __syncthreads();

    // ---- phase 2: dual MFMA linear ----
    int wave = t >> 6;           // 0..7 -> col tile
    int lane = t & 63;
    int m = lane & 15, quad = lane >> 4;
    int col = wave * 16 + m;

    bf16x8 bl[4], br[4];
#pragma unroll
    for (int ks = 0; ks < 4; ++ks) {
        bl[ks] = *(const bf16x8*)(Wl + (size_t)col * HF + ks * 32 + quad * 8);
        br[ks] = *(const bf16x8*)(Wr + (size_t)col * HF + ks * 32 + quad * 8);
    }
    float bia = bias[col];

    if (!FUSE) {
#pragma unroll
        for (int rt = 0; rt < 4; ++rt) {
            int row0 = row0b + rt * 16;
            if (row0 >= n) break;
            f32x4 acc = {0.f, 0.f, 0.f, 0.f};
            const ushort* arow = X + (size_t)(row0 + m) * HF + quad * 8;  // root row
#pragma unroll
            for (int ks = 0; ks < 4; ++ks) {
                bf16x8 a = *(const bf16x8*)(&sh[rt * 16 + m][ks * 32 + quad * 8]);
                acc = __builtin_amdgcn_mfma_f32_16x16x32_bf16(a, bl[ks], acc, 0, 0, 0);
                bf16x8 ar = *(const bf16x8*)(arow + ks * 32);
                acc = __builtin_amdgcn_mfma_f32_16x16x32_bf16(ar, br[ks], acc, 0, 0, 0);
            }
            // C/D layout: col = lane&15, row = quad*4 + reg
#pragma unroll
            for (int i = 0; i < 4; ++i) {
                int r = row0 + quad * 4 + i;
                if (r < n) {
                    float v = fmaxf(acc[i] + bia, 0.f);
                    out[(size_t)r * HF + col] = f2b(v);
                    if (EMITQ) outq[(size_t)r * HF + col] = f2q(v);
                }
            }
        }
    } else {
        // ---- FUSE: layer-2 linear kept in regs, then in-block MLP + head ----
        f32x4 accs[4];
#pragma unroll
        for (int rt = 0; rt < 4; ++rt) {
            int row0 = row0b + rt * 16;
            f32x4 acc = {0.f, 0.f, 0.f, 0.f};
            if (row0 < n) {
                const ushort* arow = X + (size_t)(row0 + m) * HF + quad * 8;
#pragma unroll
                for (int ks = 0; ks < 4; ++ks) {
                    bf16x8 a = *(const bf16x8*)(&sh[rt * 16 + m][ks * 32 + quad * 8]);
                    acc = __builtin_amdgcn_mfma_f32_16x16x32_bf16(a, bl[ks], acc, 0, 0, 0);
                    bf16x8 ar = *(const bf16x8*)(arow + ks * 32);
                    acc = __builtin_amdgcn_mfma_f32_16x16x32_bf16(ar, br[ks], acc, 0, 0, 0);
                }
            }
            accs[rt] = acc;
        }
        __syncthreads();   // all sh (gather-tile) reads complete
#pragma unroll
        for (int rt = 0; rt < 4; ++rt)
#pragma unroll
            for (int i = 0; i < 4; ++i)
                sh[rt * 16 + quad * 4 + i][col] = f2b(fmaxf(accs[rt][i] + bia, 0.f));
        __syncthreads();   // h-tile ready

        // hidden: hid = relu(h @ Wm1^T + bm1), 8 waves x 16 cols
        bf16x8 w1[4];
#pragma unroll
        for (int ks = 0; ks < 4; ++ks)
            w1[ks] = *(const bf16x8*)(Wm1b + (size_t)col * HF + ks * 32 + quad * 8);
        float hb = bm1[col];
        f32x4 hacc[4];
#pragma unroll
        for (int rt = 0; rt < 4; ++rt) {
            f32x4 acc = {0.f, 0.f, 0.f, 0.f};
#pragma unroll
            for (int ks = 0; ks < 4; ++ks) {
                bf16x8 a = *(const bf16x8*)(&sh[rt * 16 + m][ks * 32 + quad * 8]);
                acc = __builtin_amdgcn_mfma_f32_16x16x32_bf16(a, w1[ks], acc, 0, 0, 0);
            }
            hacc[rt] = acc;
        }
        __syncthreads();   // all h-tile reads complete
#pragma unroll
        for (int rt = 0; rt < 4; ++rt)
#pragma unroll
            for (int i = 0; i < 4; ++i)
                sh[rt * 16 + quad * 4 + i][col] = f2b(fmaxf(hacc[rt][i] + hb, 0.f));
        __syncthreads();   // hid-tile ready

        // head: out = sigmoid(hid @ Wm2^T + bm2); waves 0-3, row-tile = wave
        if (wave < 4) {
            bf16x8 c0f[4], c1f[4];
#pragma unroll
            for (int ks = 0; ks < 4; ++ks) {
                c0f[ks] = *(const bf16x8*)(Wm2b + (size_t)m * HF + ks * 32 + quad * 8);
                c1f[ks] = *(const bf16x8*)(Wm2b + (size_t)(16 + m) * HF + ks * 32 + quad * 8);
            }
            f32x4 o0 = {0.f, 0.f, 0.f, 0.f};
            f32x4 o1 = {0.f, 0.f, 0.f, 0.f};
#pragma unroll
            for (int ks = 0; ks < 4; ++ks) {
                bf16x8 a = *(const bf16x8*)(&sh[wave * 16 + m][ks * 32 + quad * 8]);
                o0 = __builtin_amdgcn_mfma_f32_16x16x32_bf16(a, c0f[ks], o0, 0, 0, 0);
                o1 = __builtin_amdgcn_mfma_f32_16x16x32_bf16(a, c1f[ks], o1, 0, 0, 0);
            }
            float bb0 = bm2[m];
            float bb1 = (m < 4) ? bm2[16 + m] : 0.f;
#pragma unroll
            for (int i = 0; i < 4; ++i) {
                int row = row0b + wave * 16 + quad * 4 + i;
                if (row < n) {
                    fout[(size_t)row * NC + m] = 1.0f / (1.0f + expf(-(o0[i] + bb0)));
                    if (m < 4)
                        fout[(size_t)row * NC + 16 + m] = 1.0f / (1.0f + expf(-(o1[i] + bb1)));
                }
            }
        }
    }
}

extern "C" void kernel_launch(void* const* d_in, const int* in_sizes, int n_in,
                              void* d_out, int out_size, void* d_ws, size_t ws_size,
                              hipStream_t stream) {
    const float* x   = (const float*)d_in[0];
    const int*   ei  = (const int*)d_in[1];
    const float* W1l = (const float*)d_in[2];
    const float* b1  = (const float*)d_in[3];
    const float* W1r = (const float*)d_in[4];
    const float* W2l = (const float*)d_in[5];
    const float* b2  = (const float*)d_in[6];
    const float* W2r = (const float*)d_in[7];
    const float* Wm1 = (const float*)d_in[8];
    const float* bm1 = (const float*)d_in[9];
    const float* Wm2 = (const float*)d_in[10];
    const float* bm2 = (const float*)d_in[11];
    float* out = (float*)d_out;

    const int N = NODES, E = EDGES;
    const int* src = ei;
    const int* dst = ei + E;

    // workspace layout (16B-aligned sections), ~85 MB total
    int* bcur   = (int*)d_ws;                        // 1568 ints
    uint* ebufp = (uint*)(bcur + 1568);              // NBK*CAPB uints (~8MB)
    ushort* xb  = (ushort*)(ebufp + (size_t)NBK * CAPB); // N*HF bf16
    ushort* h1  = xb + (size_t)N * HF;                   // N*HF bf16
    ushort* wb  = h1 + (size_t)N * HF;                   // 86016 bf16 weights
    uchar* xq   = (uchar*)(wb + 86016);                  // N*HF fp8
    uchar* h1q  = xq + (size_t)N * HF;                   // N*HF fp8
    ushort* wb1l = wb;
    ushort* wb1r = wb + 16384;
    ushort* wb2l = wb + 32768;
    ushort* wb2r = wb + 49152;
    ushort* wbm1 = wb + 65536;
    ushort* wbm2 = wb + 81920;

    const int n8 = N * HF / 8;

    // ---- zero bucket counters, then merged partition + converters ----
    hipMemsetAsync(bcur, 0, NBK * sizeof(int), stream);
    prep_kernel<<<NPB + XB + 336, 256, 0, stream>>>(
        x, xb, xq, W1l, W1r, W2l, W2r, Wm1, Wm2, wb, src, dst, bcur, ebufp, n8, E);

    const int fusedBlocks = (N + 63) / 64;   // == NBK: bucket grid == layer grid

    // ---- layer 1: in-block CSR + fp8 gather + dual linear, emits h1 + h1q ----
    fused_sage_layer<true, false><<<fusedBlocks, 512, 0, stream>>>(
        xq, xb, ebufp, bcur, wb1l, wb1r, b1, h1, h1q,
        nullptr, nullptr, nullptr, nullptr, nullptr, N);
    // ---- layer 2 + fused MLP hidden + head + sigmoid ----
    fused_sage_layer<false, true><<<fusedBlocks, 512, 0, stream>>>(
        h1q, h1, ebufp, bcur, wb2l, wb2r, b2, nullptr, nullptr,
        wbm1, wbm2, bm1, bm2, out, N);
}

// Round 14
// 285.824 us; speedup vs baseline: 1.7025x; 1.7025x over previous
//
#include <hip/hip_runtime.h>
#include <math.h>

#define NODES 100000
#define EDGES 1600000
#define HF 128
#define NC 20
#define CAPN 64                         // LDS edge slots/node (P(deg>=64)~2e-13 over graph)
#define BSHIFT 6
#define BNODES 64                       // nodes per bucket == nodes per layer block (1:1 grid)
#define NBK ((NODES + BNODES - 1) / BNODES)   // 1563 buckets = layer grid
#define CAPB 1280                       // bucket edge capacity (mean 1024, sd 32, +8 sigma)
#define EPB 4096                        // edges per partition block (391 blocks)
#define NPB ((EDGES + EPB - 1) / EPB)   // 391 partition blocks
#define XB2 ((NODES * HF / 16 + 255) / 256)   // converter blocks, 16 floats/thread

typedef __attribute__((ext_vector_type(8))) short bf16x8;
typedef __attribute__((ext_vector_type(4))) float f32x4;
typedef __attribute__((ext_vector_type(2))) float f32x2;

__device__ __forceinline__ ushort f2b(float f) {
    uint u = __float_as_uint(f);
    uint r = (u + 0x7FFFu + ((u >> 16) & 1u)) >> 16;
    return (ushort)r;
}
__device__ __forceinline__ uchar f2q(float f) {
    return (uchar)(__builtin_amdgcn_cvt_pk_fp8_f32(f, f, 0, false) & 0xFF);
}

// ---- merged partition + converters (one dispatch; bcur pre-zeroed) ----
// Partition = r12's 3-phase LDS structure (clear / histogram+reserve /
// scatter). r13 measured the alternative: single-pass global-atomic append
// = 241us, WRITE +75MB — the LDS histogram is what makes bucket appends
// LINE-BATCHED in time; it is load-bearing, not overhead. Partition blocks
// FIRST (latency hides under converter blocks, r2/r4).
// Entry packing: loc(dst&63)<<17 | src (src < 2^17).
__global__ void prep_kernel(const float* __restrict__ x, ushort* __restrict__ xb,
                            uchar* __restrict__ xq,
                            const float* __restrict__ a, const float* __restrict__ b,
                            const float* __restrict__ c, const float* __restrict__ d,
                            const float* __restrict__ e, const float* __restrict__ wm2,
                            ushort* __restrict__ wb,
                            const int* __restrict__ src, const int* __restrict__ dst,
                            int* __restrict__ bcur, uint* __restrict__ ebufp,
                            int n16, int E) {
    __shared__ int h[NBK];       // 6252 B
    __shared__ int basea[NBK];   // 6252 B (running global write position)
    int blk = blockIdx.x;
    int t = threadIdx.x;
    if (blk < NPB) {
        // ---- bucket-append partition of edges by dst/64 (int4 reads) ----
        int base = blk * EPB;
        const int4* d4 = (const int4*)(dst + base);   // E%4==0, base%4==0
        const int4* s4 = (const int4*)(src + base);
        for (int i = t; i < NBK; i += 256) h[i] = 0;
        __syncthreads();
#pragma unroll
        for (int it = 0; it < EPB / 1024; ++it) {
            int i4 = it * 256 + t;
            if (base + i4 * 4 < E) {
                int4 dv = d4[i4];
                atomicAdd(&h[dv.x >> BSHIFT], 1);
                atomicAdd(&h[dv.y >> BSHIFT], 1);
                atomicAdd(&h[dv.z >> BSHIFT], 1);
                atomicAdd(&h[dv.w >> BSHIFT], 1);
            }
        }
        __syncthreads();
        for (int i = t; i < NBK; i += 256) {
            int cc = h[i];
            basea[i] = cc ? (i * CAPB + atomicAdd(&bcur[i], cc)) : 0;
        }
        __syncthreads();
#pragma unroll
        for (int it = 0; it < EPB / 1024; ++it) {
            int i4 = it * 256 + t;
            if (base + i4 * 4 < E) {
                int4 dv = d4[i4];
                int4 sv = s4[i4];
                const int dd[4] = {dv.x, dv.y, dv.z, dv.w};
                const int ss[4] = {sv.x, sv.y, sv.z, sv.w};
#pragma unroll
                for (int k = 0; k < 4; ++k) {
                    int bb = dd[k] >> BSHIFT;
                    int pos = atomicAdd(&basea[bb], 1);   // slot alloc, LDS-local
                    if (pos < (bb + 1) * CAPB)            // fail-safe (8-sigma)
                        ebufp[pos] = ((uint)(dd[k] & (BNODES - 1)) << 17) | (uint)ss[k];
                }
            }
        }
    } else if (blk < NPB + XB2) {
        // ---- x -> bf16 + fp8, 16 floats/thread ----
        int i = (blk - NPB) * 256 + t;
        if (i >= n16) return;
        const float4* p = (const float4*)x + (size_t)i * 4;
        float4 v0 = p[0], v1 = p[1], v2 = p[2], v3 = p[3];
        uint4 oa, ob;
        oa.x = (uint)f2b(v0.x) | ((uint)f2b(v0.y) << 16);
        oa.y = (uint)f2b(v0.z) | ((uint)f2b(v0.w) << 16);
        oa.z = (uint)f2b(v1.x) | ((uint)f2b(v1.y) << 16);
        oa.w = (uint)f2b(v1.z) | ((uint)f2b(v1.w) << 16);
        ob.x = (uint)f2b(v2.x) | ((uint)f2b(v2.y) << 16);
        ob.y = (uint)f2b(v2.z) | ((uint)f2b(v2.w) << 16);
        ob.z = (uint)f2b(v3.x) | ((uint)f2b(v3.y) << 16);
        ob.w = (uint)f2b(v3.z) | ((uint)f2b(v3.w) << 16);
        ((uint4*)xb)[i * 2]     = oa;
        ((uint4*)xb)[i * 2 + 1] = ob;
        uint4 q;
        q.x = __builtin_amdgcn_cvt_pk_fp8_f32(v0.x, v0.y, 0, false);
        q.x = __builtin_amdgcn_cvt_pk_fp8_f32(v0.z, v0.w, q.x, true);
        q.y = __builtin_amdgcn_cvt_pk_fp8_f32(v1.x, v1.y, 0, false);
        q.y = __builtin_amdgcn_cvt_pk_fp8_f32(v1.z, v1.w, q.y, true);
        q.z = __builtin_amdgcn_cvt_pk_fp8_f32(v2.x, v2.y, 0, false);
        q.z = __builtin_amdgcn_cvt_pk_fp8_f32(v2.z, v2.w, q.z, true);
        q.w = __builtin_amdgcn_cvt_pk_fp8_f32(v3.x, v3.y, 0, false);
        q.w = __builtin_amdgcn_cvt_pk_fp8_f32(v3.z, v3.w, q.w, true);
        ((uint4*)xq)[i] = q;
    } else {
        // ---- weights -> bf16 ----
        int i = (blk - NPB - XB2) * 256 + t;
        if (i < 81920) {
            const float* srcs[5] = {a, b, c, d, e};
            wb[i] = f2b(srcs[i >> 14][i & 16383]);
        } else if (i < 86016) {
            int j = i - 81920;
            wb[i] = ((j >> 7) < NC) ? f2b(wm2[j]) : (ushort)0;
        }
    }
}

// ---- fused SAGE layer: out = relu(bias + mean_agg(Xq)@Wl^T + X@Wr^T) ----
// Phase 0: read THIS block's bucket segment (~1024 packed entries, 4KB
//   contiguous) and slot-scatter into sidx via 64 LDS counters — the CSR
//   build, fused (r11: FETCH 101.5->91.2MB). Offsets pre-scaled <<7.
// Phase 1: W=4 exec-masked gather — FROZEN. Five mechanistically distinct
//   attacks (W=8 branchy, depth-2 pipeline, branchless clamp-W8, f32 root,
//   NT/zero-row) all landed 86-112us vs this structure's 86-89. FETCH is at
//   the 8-XCD compulsory floor (91MB ~= 8 x Xq); the residual is random-
//   128B-line DRAM behavior, not CU issue capacity.
// Phase 2: 8 waves MFMA dual linear.
// FUSE (layer 2): in-block MLP hidden + head. Head o0/o1 split across
//   waves 0-3 / 4-7 (was: waves 4-7 idle, o0+o1 serial in waves 0-3).
template<bool EMITQ, bool FUSE>
__global__ __launch_bounds__(512)
void fused_sage_layer(const uchar* __restrict__ Xq, const ushort* __restrict__ X,
                      const uint* __restrict__ ebufp, const int* __restrict__ bcur,
                      const ushort* __restrict__ Wl, const ushort* __restrict__ Wr,
                      const float* __restrict__ bias, ushort* __restrict__ out,
                      uchar* __restrict__ outq,
                      const ushort* __restrict__ Wm1b, const ushort* __restrict__ Wm2b,
                      const float* __restrict__ bm1, const float* __restrict__ bm2,
                      float* __restrict__ fout, int n) {
    __shared__ ushort sh[64][136];     // 17408 B (gather tile; h/hid tile in FUSE)
    __shared__ int sidx[64 * CAPN];    // 16384 B (byte offsets, pre-scaled)
    __shared__ int lcnt[64];
    int row0b = blockIdx.x * 64;
    int t = threadIdx.x;

    // ---- phase 0: in-block CSR build from bucket segment ----
    if (t < 64) lcnt[t] = 0;
    __syncthreads();
    int cb = min(bcur[blockIdx.x], CAPB);
    const uint* ep = ebufp + (size_t)blockIdx.x * CAPB;
    for (int i = t; i < cb; i += 512) {
        uint e = ep[i];
        int loc = (int)(e >> 17);
        int slot = atomicAdd(&lcnt[loc], 1);
        if (slot < CAPN)                  // fail-safe (P ~ 2e-13)
            sidx[loc * CAPN + slot] = (int)((e & 0x1FFFFu) << 7);
    }
    __syncthreads();

    // ---- phase 1: fp8 gather (W=4 exec-masked) ----
    {
        int grp = t >> 5;              // 0..15: node group
        int sub = t & 31;
        int sel = sub >> 3;            // 0..3: edge interleave
        int cg = sub & 7;              // col-group: 16 fp8 cols = 16 B
        const uchar* xc = Xq + cg * 16;
#pragma unroll
        for (int batch = 0; batch < 4; ++batch) {
            int nloc = batch * 16 + grp;
            int node = row0b + nloc;
            int len = min(lcnt[nloc], CAPN);
            int sbase = nloc * CAPN;
            f32x2 acc2[8];
#pragma unroll
            for (int i = 0; i < 8; ++i) acc2[i] = f32x2{0.f, 0.f};
            for (int e = 0; e < len; e += 16) {
                uint4 v[4];
#pragma unroll
                for (int w = 0; w < 4; ++w) {
                    int ee = e + 4 * w + sel;
                    int off = sidx[sbase + ee];       // in-window; garbage if masked
                    uint4 vv = {0u, 0u, 0u, 0u};
                    if (ee < len) vv = *(const uint4*)(xc + (size_t)(uint)off);
                    v[w] = vv;                        // fp8 0x00 -> +0.0f
                }
#pragma unroll
                for (int w = 0; w < 4; ++w) {
                    const uint* pp = (const uint*)&v[w];
#pragma unroll
                    for (int i = 0; i < 4; ++i) {
                        acc2[2 * i]     += __builtin_amdgcn_cvt_pk_f32_fp8(pp[i], false);
                        acc2[2 * i + 1] += __builtin_amdgcn_cvt_pk_f32_fp8(pp[i], true);
                    }
                }
            }
#pragma unroll
            for (int i = 0; i < 8; ++i) {
                acc2[i].x += __shfl_xor(acc2[i].x, 8);
                acc2[i].x += __shfl_xor(acc2[i].x, 16);
                acc2[i].y += __shfl_xor(acc2[i].y, 8);
                acc2[i].y += __shfl_xor(acc2[i].y, 16);
            }
            if (sel == 0 && node < n) {
                float invd = 1.0f / fmaxf((float)len, 1.0f);
                uint4 o0, o1;
                uint* p0 = (uint*)&o0;
                uint* p1 = (uint*)&o1;
#pragma unroll
                for (int i = 0; i < 4; ++i) {
                    p0[i] = (uint)f2b(acc2[i].x * invd) | ((uint)f2b(acc2[i].y * invd) << 16);
                    p1[i] = (uint)f2b(acc2[4 + i].x * invd) | ((uint)f2b(acc2[4 + i].y * invd) << 16);
                }
                *(uint4*)(&sh[nloc][cg * 16]) = o0;
                *(uint4*)(&sh[nloc][cg * 16 + 8]) = o1;
            }
        }
    }
    __syncthreads();

    // ---- phase 2: dual MFMA linear ----
    int wave = t >> 6;           // 0..7 -> col tile
    int lane = t & 63;
    int m = lane & 15, quad = lane >> 4;
    int col = wave * 16 + m;

    bf16x8 bl[4], br[4];
#pragma unroll
    for (int ks = 0; ks < 4; ++ks) {
        bl[ks] = *(const bf16x8*)(Wl + (size_t)col * HF + ks * 32 + quad * 8);
        br[ks] = *(const bf16x8*)(Wr + (size_t)col * HF + ks * 32 + quad * 8);
    }
    float bia = bias[col];

    if (!FUSE) {
#pragma unroll
        for (int rt = 0; rt < 4; ++rt) {
            int row0 = row0b + rt * 16;
            if (row0 >= n) break;
            f32x4 acc = {0.f, 0.f, 0.f, 0.f};
            const ushort* arow = X + (size_t)(row0 + m) * HF + quad * 8;  // root row
#pragma unroll
            for (int ks = 0; ks < 4; ++ks) {
                bf16x8 a = *(const bf16x8*)(&sh[rt * 16 + m][ks * 32 + quad * 8]);
                acc = __builtin_amdgcn_mfma_f32_16x16x32_bf16(a, bl[ks], acc, 0, 0, 0);
                bf16x8 ar = *(const bf16x8*)(arow + ks * 32);
                acc = __builtin_amdgcn_mfma_f32_16x16x32_bf16(ar, br[ks], acc, 0, 0, 0);
            }
            // C/D layout: col = lane&15, row = quad*4 + reg
#pragma unroll
            for (int i = 0; i < 4; ++i) {
                int r = row0 + quad * 4 + i;
                if (r < n) {
                    float v = fmaxf(acc[i] + bia, 0.f);
                    out[(size_t)r * HF + col] = f2b(v);
                    if (EMITQ) outq[(size_t)r * HF + col] = f2q(v);
                }
            }
        }
    } else {
        // ---- FUSE: layer-2 linear kept in regs, then in-block MLP + head ----
        f32x4 accs[4];
#pragma unroll
        for (int rt = 0; rt < 4; ++rt) {
            int row0 = row0b + rt * 16;
            f32x4 acc = {0.f, 0.f, 0.f, 0.f};
            if (row0 < n) {
                const ushort* arow = X + (size_t)(row0 + m) * HF + quad * 8;
#pragma unroll
                for (int ks = 0; ks < 4; ++ks) {
                    bf16x8 a = *(const bf16x8*)(&sh[rt * 16 + m][ks * 32 + quad * 8]);
                    acc = __builtin_amdgcn_mfma_f32_16x16x32_bf16(a, bl[ks], acc, 0, 0, 0);
                    bf16x8 ar = *(const bf16x8*)(arow + ks * 32);
                    acc = __builtin_amdgcn_mfma_f32_16x16x32_bf16(ar, br[ks], acc, 0, 0, 0);
                }
            }
            accs[rt] = acc;
        }
        __syncthreads();   // all sh (gather-tile) reads complete
#pragma unroll
        for (int rt = 0; rt < 4; ++rt)
#pragma unroll
            for (int i = 0; i < 4; ++i)
                sh[rt * 16 + quad * 4 + i][col] = f2b(fmaxf(accs[rt][i] + bia, 0.f));
        __syncthreads();   // h-tile ready

        // hidden: hid = relu(h @ Wm1^T + bm1), 8 waves x 16 cols
        bf16x8 w1[4];
#pragma unroll
        for (int ks = 0; ks < 4; ++ks)
            w1[ks] = *(const bf16x8*)(Wm1b + (size_t)col * HF + ks * 32 + quad * 8);
        float hb = bm1[col];
        f32x4 hacc[4];
#pragma unroll
        for (int rt = 0; rt < 4; ++rt) {
            f32x4 acc = {0.f, 0.f, 0.f, 0.f};
#pragma unroll
            for (int ks = 0; ks < 4; ++ks) {
                bf16x8 a = *(const bf16x8*)(&sh[rt * 16 + m][ks * 32 + quad * 8]);
                acc = __builtin_amdgcn_mfma_f32_16x16x32_bf16(a, w1[ks], acc, 0, 0, 0);
            }
            hacc[rt] = acc;
        }
        __syncthreads();   // all h-tile reads complete
#pragma unroll
        for (int rt = 0; rt < 4; ++rt)
#pragma unroll
            for (int i = 0; i < 4; ++i)
                sh[rt * 16 + quad * 4 + i][col] = f2b(fmaxf(hacc[rt][i] + hb, 0.f));
        __syncthreads();   // hid-tile ready

        // head: out = sigmoid(hid @ Wm2^T + bm2)
        // waves 0-3: o0 (cols 0-15) of row-tile w; waves 4-7: o1 (cols 16-19)
        // of row-tile w-4 — halves the serial head tail vs o0+o1 in one wave.
        {
            int rtile = wave & 3;
            bool hiHalf = wave >= 4;
            int wcol = hiHalf ? (16 + m) : m;
            bf16x8 cf[4];
#pragma unroll
            for (int ks = 0; ks < 4; ++ks)
                cf[ks] = *(const bf16x8*)(Wm2b + (size_t)wcol * HF + ks * 32 + quad * 8);
            f32x4 o = {0.f, 0.f, 0.f, 0.f};
#pragma unroll
            for (int ks = 0; ks < 4; ++ks) {
                bf16x8 a = *(const bf16x8*)(&sh[rtile * 16 + m][ks * 32 + quad * 8]);
                o = __builtin_amdgcn_mfma_f32_16x16x32_bf16(a, cf[ks], o, 0, 0, 0);
            }
            bool valid = !hiHalf || (m < 4);   // cols 16-19 only
            float bb = valid ? bm2[wcol] : 0.f;
#pragma unroll
            for (int i = 0; i < 4; ++i) {
                int row = row0b + rtile * 16 + quad * 4 + i;
                if (row < n && valid)
                    fout[(size_t)row * NC + wcol] = 1.0f / (1.0f + expf(-(o[i] + bb)));
            }
        }
    }
}

extern "C" void kernel_launch(void* const* d_in, const int* in_sizes, int n_in,
                              void* d_out, int out_size, void* d_ws, size_t ws_size,
                              hipStream_t stream) {
    const float* x   = (const float*)d_in[0];
    const int*   ei  = (const int*)d_in[1];
    const float* W1l = (const float*)d_in[2];
    const float* b1  = (const float*)d_in[3];
    const float* W1r = (const float*)d_in[4];
    const float* W2l = (const float*)d_in[5];
    const float* b2  = (const float*)d_in[6];
    const float* W2r = (const float*)d_in[7];
    const float* Wm1 = (const float*)d_in[8];
    const float* bm1 = (const float*)d_in[9];
    const float* Wm2 = (const float*)d_in[10];
    const float* bm2 = (const float*)d_in[11];
    float* out = (float*)d_out;

    const int N = NODES, E = EDGES;
    const int* src = ei;
    const int* dst = ei + E;

    // workspace layout (16B-aligned sections), ~85 MB total
    int* bcur   = (int*)d_ws;                        // 1568 ints
    uint* ebufp = (uint*)(bcur + 1568);              // NBK*CAPB uints (~8MB)
    ushort* xb  = (ushort*)(ebufp + (size_t)NBK * CAPB); // N*HF bf16
    ushort* h1  = xb + (size_t)N * HF;                   // N*HF bf16
    ushort* wb  = h1 + (size_t)N * HF;                   // 86016 bf16 weights
    uchar* xq   = (uchar*)(wb + 86016);                  // N*HF fp8
    uchar* h1q  = xq + (size_t)N * HF;                   // N*HF fp8
    ushort* wb1l = wb;
    ushort* wb1r = wb + 16384;
    ushort* wb2l = wb + 32768;
    ushort* wb2r = wb + 49152;
    ushort* wbm1 = wb + 65536;
    ushort* wbm2 = wb + 81920;

    const int n16 = N * HF / 16;

    // ---- zero bucket counters, then merged partition + converters ----
    hipMemsetAsync(bcur, 0, NBK * sizeof(int), stream);
    prep_kernel<<<NPB + XB2 + 336, 256, 0, stream>>>(
        x, xb, xq, W1l, W1r, W2l, W2r, Wm1, Wm2, wb, src, dst, bcur, ebufp, n16, E);

    const int fusedBlocks = (N + 63) / 64;   // == NBK: bucket grid == layer grid

    // ---- layer 1: in-block CSR + fp8 gather + dual linear, emits h1 + h1q ----
    fused_sage_layer<true, false><<<fusedBlocks, 512, 0, stream>>>(
        xq, xb, ebufp, bcur, wb1l, wb1r, b1, h1, h1q,
        nullptr, nullptr, nullptr, nullptr, nullptr, N);
    // ---- layer 2 + fused MLP hidden + head + sigmoid ----
    fused_sage_layer<false, true><<<fusedBlocks, 512, 0, stream>>>(
        h1q, h1, ebufp, bcur, wb2l, wb2r, b2, nullptr, nullptr,
        wbm1, wbm2, bm1, bm2, out, N);
}

// Round 15
// 276.552 us; speedup vs baseline: 1.7595x; 1.0335x over previous
//
#include <hip/hip_runtime.h>
#include <math.h>

#define NODES 100000
#define EDGES 1600000
#define HF 128
#define NC 20
#define CAPN 64                         // LDS edge slots/node (P(deg>=64)~2e-13 over graph)
#define BSHIFT 6
#define BNODES 64                       // nodes per bucket == nodes per layer block (1:1 grid)
#define NBK ((NODES + BNODES - 1) / BNODES)   // 1563 buckets = layer grid
#define CAPB 1280                       // bucket edge capacity (mean 1024, sd 32, +8 sigma)
#define EPB 4096                        // edges per partition block (391 blocks)
#define NPB ((EDGES + EPB - 1) / EPB)   // 391 partition blocks
#define XB2 ((NODES * HF / 16 + 255) / 256)   // converter blocks, 16 floats/thread

typedef __attribute__((ext_vector_type(8))) short bf16x8;
typedef __attribute__((ext_vector_type(4))) float f32x4;
typedef __attribute__((ext_vector_type(2))) float f32x2;

__device__ __forceinline__ ushort f2b(float f) {
    uint u = __float_as_uint(f);
    uint r = (u + 0x7FFFu + ((u >> 16) & 1u)) >> 16;
    return (ushort)r;
}
__device__ __forceinline__ uchar f2q(float f) {
    return (uchar)(__builtin_amdgcn_cvt_pk_fp8_f32(f, f, 0, false) & 0xFF);
}

// ---- merged partition + converters (one dispatch; bcur pre-zeroed) ----
// Partition = 3-phase LDS structure (clear / histogram+reserve / scatter).
// r13 measured the alternative (single-pass global-atomic append): 241us,
// WRITE +75MB — the LDS histogram is what makes bucket appends LINE-BATCHED
// in time; it is load-bearing. Partition blocks FIRST (r2/r4).
// Entry packing: loc(dst&63)<<17 | src (src < 2^17).
__global__ void prep_kernel(const float* __restrict__ x, ushort* __restrict__ xb,
                            uchar* __restrict__ xq,
                            const float* __restrict__ a, const float* __restrict__ b,
                            const float* __restrict__ c, const float* __restrict__ d,
                            const float* __restrict__ e, const float* __restrict__ wm2,
                            ushort* __restrict__ wb,
                            const int* __restrict__ src, const int* __restrict__ dst,
                            int* __restrict__ bcur, uint* __restrict__ ebufp,
                            int n16, int E) {
    __shared__ int h[NBK];       // 6252 B
    __shared__ int basea[NBK];   // 6252 B (running global write position)
    int blk = blockIdx.x;
    int t = threadIdx.x;
    if (blk < NPB) {
        // ---- bucket-append partition of edges by dst/64 (int4 reads) ----
        int base = blk * EPB;
        const int4* d4 = (const int4*)(dst + base);   // E%4==0, base%4==0
        const int4* s4 = (const int4*)(src + base);
        for (int i = t; i < NBK; i += 256) h[i] = 0;
        __syncthreads();
#pragma unroll
        for (int it = 0; it < EPB / 1024; ++it) {
            int i4 = it * 256 + t;
            if (base + i4 * 4 < E) {
                int4 dv = d4[i4];
                atomicAdd(&h[dv.x >> BSHIFT], 1);
                atomicAdd(&h[dv.y >> BSHIFT], 1);
                atomicAdd(&h[dv.z >> BSHIFT], 1);
                atomicAdd(&h[dv.w >> BSHIFT], 1);
            }
        }
        __syncthreads();
        for (int i = t; i < NBK; i += 256) {
            int cc = h[i];
            basea[i] = cc ? (i * CAPB + atomicAdd(&bcur[i], cc)) : 0;
        }
        __syncthreads();
#pragma unroll
        for (int it = 0; it < EPB / 1024; ++it) {
            int i4 = it * 256 + t;
            if (base + i4 * 4 < E) {
                int4 dv = d4[i4];
                int4 sv = s4[i4];
                const int dd[4] = {dv.x, dv.y, dv.z, dv.w};
                const int ss[4] = {sv.x, sv.y, sv.z, sv.w};
#pragma unroll
                for (int k = 0; k < 4; ++k) {
                    int bb = dd[k] >> BSHIFT;
                    int pos = atomicAdd(&basea[bb], 1);   // slot alloc, LDS-local
                    if (pos < (bb + 1) * CAPB)            // fail-safe (8-sigma)
                        ebufp[pos] = ((uint)(dd[k] & (BNODES - 1)) << 17) | (uint)ss[k];
                }
            }
        }
    } else if (blk < NPB + XB2) {
        // ---- x -> bf16 + fp8, 16 floats/thread ----
        int i = (blk - NPB) * 256 + t;
        if (i >= n16) return;
        const float4* p = (const float4*)x + (size_t)i * 4;
        float4 v0 = p[0], v1 = p[1], v2 = p[2], v3 = p[3];
        uint4 oa, ob;
        oa.x = (uint)f2b(v0.x) | ((uint)f2b(v0.y) << 16);
        oa.y = (uint)f2b(v0.z) | ((uint)f2b(v0.w) << 16);
        oa.z = (uint)f2b(v1.x) | ((uint)f2b(v1.y) << 16);
        oa.w = (uint)f2b(v1.z) | ((uint)f2b(v1.w) << 16);
        ob.x = (uint)f2b(v2.x) | ((uint)f2b(v2.y) << 16);
        ob.y = (uint)f2b(v2.z) | ((uint)f2b(v2.w) << 16);
        ob.z = (uint)f2b(v3.x) | ((uint)f2b(v3.y) << 16);
        ob.w = (uint)f2b(v3.z) | ((uint)f2b(v3.w) << 16);
        ((uint4*)xb)[i * 2]     = oa;
        ((uint4*)xb)[i * 2 + 1] = ob;
        uint4 q;
        q.x = __builtin_amdgcn_cvt_pk_fp8_f32(v0.x, v0.y, 0, false);
        q.x = __builtin_amdgcn_cvt_pk_fp8_f32(v0.z, v0.w, q.x, true);
        q.y = __builtin_amdgcn_cvt_pk_fp8_f32(v1.x, v1.y, 0, false);
        q.y = __builtin_amdgcn_cvt_pk_fp8_f32(v1.z, v1.w, q.y, true);
        q.z = __builtin_amdgcn_cvt_pk_fp8_f32(v2.x, v2.y, 0, false);
        q.z = __builtin_amdgcn_cvt_pk_fp8_f32(v2.z, v2.w, q.z, true);
        q.w = __builtin_amdgcn_cvt_pk_fp8_f32(v3.x, v3.y, 0, false);
        q.w = __builtin_amdgcn_cvt_pk_fp8_f32(v3.z, v3.w, q.w, true);
        ((uint4*)xq)[i] = q;
    } else {
        // ---- weights -> bf16 ----
        int i = (blk - NPB - XB2) * 256 + t;
        if (i < 81920) {
            const float* srcs[5] = {a, b, c, d, e};
            wb[i] = f2b(srcs[i >> 14][i & 16383]);
        } else if (i < 86016) {
            int j = i - 81920;
            wb[i] = ((j >> 7) < NC) ? f2b(wm2[j]) : (ushort)0;
        }
    }
}

// ---- fused SAGE layer: out = relu(bias + mean_agg(Xq)@Wl^T + X@Wr^T) ----
// Phase 0: read THIS block's bucket segment (~1024 packed entries, 4KB
//   contiguous) and slot-scatter into sidx via 64 LDS counters — the CSR
//   build, fused (r11). Offsets pre-scaled <<7.
// Phase 1: W=8 exec-masked gather (stride-32 rounds). Little's law: 0.6
//   req/ns/CU x 500ns latency needs ~300 in-flight/CU; W=4 gave ~80.
//   r3's W=8 failed at VGPR 72 / occ 20% from a 40-VGPR base; r14's base
//   is 32 VGPR, and __launch_bounds__(512,8) pins 8 waves/EU (VGPR<=64,
//   4 blocks/CU — LDS 34.3KB allows exactly 4). Pre-commit: VGPR>64 or
//   occ<40% -> revert; flat dur at good occ -> fabric floor, plateau.
// Phase 2: 8 waves MFMA dual linear.
// FUSE (layer 2): in-block MLP hidden + head; head o0/o1 split across
//   waves 0-3 / 4-7 (r14: -4us, VGPR 40->32).
template<bool EMITQ, bool FUSE>
__global__ __launch_bounds__(512, 8)
void fused_sage_layer(const uchar* __restrict__ Xq, const ushort* __restrict__ X,
                      const uint* __restrict__ ebufp, const int* __restrict__ bcur,
                      const ushort* __restrict__ Wl, const ushort* __restrict__ Wr,
                      const float* __restrict__ bias, ushort* __restrict__ out,
                      uchar* __restrict__ outq,
                      const ushort* __restrict__ Wm1b, const ushort* __restrict__ Wm2b,
                      const float* __restrict__ bm1, const float* __restrict__ bm2,
                      float* __restrict__ fout, int n) {
    __shared__ ushort sh[64][136];     // 17408 B (gather tile; h/hid tile in FUSE)
    __shared__ int sidx[64 * CAPN];    // 16384 B (byte offsets, pre-scaled)
    __shared__ int lcnt[64];
    int row0b = blockIdx.x * 64;
    int t = threadIdx.x;

    // ---- phase 0: in-block CSR build from bucket segment ----
    if (t < 64) lcnt[t] = 0;
    __syncthreads();
    int cb = min(bcur[blockIdx.x], CAPB);
    const uint* ep = ebufp + (size_t)blockIdx.x * CAPB;
    for (int i = t; i < cb; i += 512) {
        uint e = ep[i];
        int loc = (int)(e >> 17);
        int slot = atomicAdd(&lcnt[loc], 1);
        if (slot < CAPN)                  // fail-safe (P ~ 2e-13)
            sidx[loc * CAPN + slot] = (int)((e & 0x1FFFFu) << 7);
    }
    __syncthreads();

    // ---- phase 1: fp8 gather (W=8 exec-masked, stride-32 rounds) ----
    {
        int grp = t >> 5;              // 0..15: node group
        int sub = t & 31;
        int sel = sub >> 3;            // 0..3: edge interleave
        int cg = sub & 7;              // col-group: 16 fp8 cols = 16 B
        const uchar* xc = Xq + cg * 16;
#pragma unroll
        for (int batch = 0; batch < 4; ++batch) {
            int nloc = batch * 16 + grp;
            int node = row0b + nloc;
            int len = min(lcnt[nloc], CAPN);
            int sbase = nloc * CAPN;
            f32x2 acc2[8];
#pragma unroll
            for (int i = 0; i < 8; ++i) acc2[i] = f32x2{0.f, 0.f};
            for (int e = 0; e < len; e += 32) {
                uint4 v[8];
#pragma unroll
                for (int w = 0; w < 8; ++w) {
                    int ee = e + 4 * w + sel;
                    int off = sidx[sbase + min(ee, CAPN - 1)]; // in-window addr
                    uint4 vv = {0u, 0u, 0u, 0u};
                    if (ee < len) vv = *(const uint4*)(xc + (size_t)(uint)off);
                    v[w] = vv;                        // fp8 0x00 -> +0.0f
                }
#pragma unroll
                for (int w = 0; w < 8; ++w) {
                    const uint* pp = (const uint*)&v[w];
#pragma unroll
                    for (int i = 0; i < 4; ++i) {
                        acc2[2 * i]     += __builtin_amdgcn_cvt_pk_f32_fp8(pp[i], false);
                        acc2[2 * i + 1] += __builtin_amdgcn_cvt_pk_f32_fp8(pp[i], true);
                    }
                }
            }
#pragma unroll
            for (int i = 0; i < 8; ++i) {
                acc2[i].x += __shfl_xor(acc2[i].x, 8);
                acc2[i].x += __shfl_xor(acc2[i].x, 16);
                acc2[i].y += __shfl_xor(acc2[i].y, 8);
                acc2[i].y += __shfl_xor(acc2[i].y, 16);
            }
            if (sel == 0 && node < n) {
                float invd = 1.0f / fmaxf((float)len, 1.0f);
                uint4 o0, o1;
                uint* p0 = (uint*)&o0;
                uint* p1 = (uint*)&o1;
#pragma unroll
                for (int i = 0; i < 4; ++i) {
                    p0[i] = (uint)f2b(acc2[i].x * invd) | ((uint)f2b(acc2[i].y * invd) << 16);
                    p1[i] = (uint)f2b(acc2[4 + i].x * invd) | ((uint)f2b(acc2[4 + i].y * invd) << 16);
                }
                *(uint4*)(&sh[nloc][cg * 16]) = o0;
                *(uint4*)(&sh[nloc][cg * 16 + 8]) = o1;
            }
        }
    }
    __syncthreads();

    // ---- phase 2: dual MFMA linear ----
    int wave = t >> 6;           // 0..7 -> col tile
    int lane = t & 63;
    int m = lane & 15, quad = lane >> 4;
    int col = wave * 16 + m;

    bf16x8 bl[4], br[4];
#pragma unroll
    for (int ks = 0; ks < 4; ++ks) {
        bl[ks] = *(const bf16x8*)(Wl + (size_t)col * HF + ks * 32 + quad * 8);
        br[ks] = *(const bf16x8*)(Wr + (size_t)col * HF + ks * 32 + quad * 8);
    }
    float bia = bias[col];

    if (!FUSE) {
#pragma unroll
        for (int rt = 0; rt < 4; ++rt) {
            int row0 = row0b + rt * 16;
            if (row0 >= n) break;
            f32x4 acc = {0.f, 0.f, 0.f, 0.f};
            const ushort* arow = X + (size_t)(row0 + m) * HF + quad * 8;  // root row
#pragma unroll
            for (int ks = 0; ks < 4; ++ks) {
                bf16x8 a = *(const bf16x8*)(&sh[rt * 16 + m][ks * 32 + quad * 8]);
                acc = __builtin_amdgcn_mfma_f32_16x16x32_bf16(a, bl[ks], acc, 0, 0, 0);
                bf16x8 ar = *(const bf16x8*)(arow + ks * 32);
                acc = __builtin_amdgcn_mfma_f32_16x16x32_bf16(ar, br[ks], acc, 0, 0, 0);
            }
            // C/D layout: col = lane&15, row = quad*4 + reg
#pragma unroll
            for (int i = 0; i < 4; ++i) {
                int r = row0 + quad * 4 + i;
                if (r < n) {
                    float v = fmaxf(acc[i] + bia, 0.f);
                    out[(size_t)r * HF + col] = f2b(v);
                    if (EMITQ) outq[(size_t)r * HF + col] = f2q(v);
                }
            }
        }
    } else {
        // ---- FUSE: layer-2 linear kept in regs, then in-block MLP + head ----
        f32x4 accs[4];
#pragma unroll
        for (int rt = 0; rt < 4; ++rt) {
            int row0 = row0b + rt * 16;
            f32x4 acc = {0.f, 0.f, 0.f, 0.f};
            if (row0 < n) {
                const ushort* arow = X + (size_t)(row0 + m) * HF + quad * 8;
#pragma unroll
                for (int ks = 0; ks < 4; ++ks) {
                    bf16x8 a = *(const bf16x8*)(&sh[rt * 16 + m][ks * 32 + quad * 8]);
                    acc = __builtin_amdgcn_mfma_f32_16x16x32_bf16(a, bl[ks], acc, 0, 0, 0);
                    bf16x8 ar = *(const bf16x8*)(arow + ks * 32);
                    acc = __builtin_amdgcn_mfma_f32_16x16x32_bf16(ar, br[ks], acc, 0, 0, 0);
                }
            }
            accs[rt] = acc;
        }
        __syncthreads();   // all sh (gather-tile) reads complete
#pragma unroll
        for (int rt = 0; rt < 4; ++rt)
#pragma unroll
            for (int i = 0; i < 4; ++i)
                sh[rt * 16 + quad * 4 + i][col] = f2b(fmaxf(accs[rt][i] + bia, 0.f));
        __syncthreads();   // h-tile ready

        // hidden: hid = relu(h @ Wm1^T + bm1), 8 waves x 16 cols
        bf16x8 w1[4];
#pragma unroll
        for (int ks = 0; ks < 4; ++ks)
            w1[ks] = *(const bf16x8*)(Wm1b + (size_t)col * HF + ks * 32 + quad * 8);
        float hb = bm1[col];
        f32x4 hacc[4];
#pragma unroll
        for (int rt = 0; rt < 4; ++rt) {
            f32x4 acc = {0.f, 0.f, 0.f, 0.f};
#pragma unroll
            for (int ks = 0; ks < 4; ++ks) {
                bf16x8 a = *(const bf16x8*)(&sh[rt * 16 + m][ks * 32 + quad * 8]);
                acc = __builtin_amdgcn_mfma_f32_16x16x32_bf16(a, w1[ks], acc, 0, 0, 0);
            }
            hacc[rt] = acc;
        }
        __syncthreads();   // all h-tile reads complete
#pragma unroll
        for (int rt = 0; rt < 4; ++rt)
#pragma unroll
            for (int i = 0; i < 4; ++i)
                sh[rt * 16 + quad * 4 + i][col] = f2b(fmaxf(hacc[rt][i] + hb, 0.f));
        __syncthreads();   // hid-tile ready

        // head: out = sigmoid(hid @ Wm2^T + bm2)
        // waves 0-3: cols 0-15 of row-tile w; waves 4-7: cols 16-19 of
        // row-tile w-4 — halves the serial head tail.
        {
            int rtile = wave & 3;
            bool hiHalf = wave >= 4;
            int wcol = hiHalf ? (16 + m) : m;
            bf16x8 cf[4];
#pragma unroll
            for (int ks = 0; ks < 4; ++ks)
                cf[ks] = *(const bf16x8*)(Wm2b + (size_t)wcol * HF + ks * 32 + quad * 8);
            f32x4 o = {0.f, 0.f, 0.f, 0.f};
#pragma unroll
            for (int ks = 0; ks < 4; ++ks) {
                bf16x8 a = *(const bf16x8*)(&sh[rtile * 16 + m][ks * 32 + quad * 8]);
                o = __builtin_amdgcn_mfma_f32_16x16x32_bf16(a, cf[ks], o, 0, 0, 0);
            }
            bool valid = !hiHalf || (m < 4);   // cols 16-19 only
            float bb = valid ? bm2[wcol] : 0.f;
#pragma unroll
            for (int i = 0; i < 4; ++i) {
                int row = row0b + rtile * 16 + quad * 4 + i;
                if (row < n && valid)
                    fout[(size_t)row * NC + wcol] = 1.0f / (1.0f + expf(-(o[i] + bb)));
            }
        }
    }
}

extern "C" void kernel_launch(void* const* d_in, const int* in_sizes, int n_in,
                              void* d_out, int out_size, void* d_ws, size_t ws_size,
                              hipStream_t stream) {
    const float* x   = (const float*)d_in[0];
    const int*   ei  = (const int*)d_in[1];
    const float* W1l = (const float*)d_in[2];
    const float* b1  = (const float*)d_in[3];
    const float* W1r = (const float*)d_in[4];
    const float* W2l = (const float*)d_in[5];
    const float* b2  = (const float*)d_in[6];
    const float* W2r = (const float*)d_in[7];
    const float* Wm1 = (const float*)d_in[8];
    const float* bm1 = (const float*)d_in[9];
    const float* Wm2 = (const float*)d_in[10];
    const float* bm2 = (const float*)d_in[11];
    float* out = (float*)d_out;

    const int N = NODES, E = EDGES;
    const int* src = ei;
    const int* dst = ei + E;

    // workspace layout (16B-aligned sections), ~85 MB total
    int* bcur   = (int*)d_ws;                        // 1568 ints
    uint* ebufp = (uint*)(bcur + 1568);              // NBK*CAPB uints (~8MB)
    ushort* xb  = (ushort*)(ebufp + (size_t)NBK * CAPB); // N*HF bf16
    ushort* h1  = xb + (size_t)N * HF;                   // N*HF bf16
    ushort* wb  = h1 + (size_t)N * HF;                   // 86016 bf16 weights
    uchar* xq   = (uchar*)(wb + 86016);                  // N*HF fp8
    uchar* h1q  = xq + (size_t)N * HF;                   // N*HF fp8
    ushort* wb1l = wb;
    ushort* wb1r = wb + 16384;
    ushort* wb2l = wb + 32768;
    ushort* wb2r = wb + 49152;
    ushort* wbm1 = wb + 65536;
    ushort* wbm2 = wb + 81920;

    const int n16 = N * HF / 16;

    // ---- zero bucket counters, then merged partition + converters ----
    hipMemsetAsync(bcur, 0, NBK * sizeof(int), stream);
    prep_kernel<<<NPB + XB2 + 336, 256, 0, stream>>>(
        x, xb, xq, W1l, W1r, W2l, W2r, Wm1, Wm2, wb, src, dst, bcur, ebufp, n16, E);

    const int fusedBlocks = (N + 63) / 64;   // == NBK: bucket grid == layer grid

    // ---- layer 1: in-block CSR + fp8 gather + dual linear, emits h1 + h1q ----
    fused_sage_layer<true, false><<<fusedBlocks, 512, 0, stream>>>(
        xq, xb, ebufp, bcur, wb1l, wb1r, b1, h1, h1q,
        nullptr, nullptr, nullptr, nullptr, nullptr, N);
    // ---- layer 2 + fused MLP hidden + head + sigmoid ----
    fused_sage_layer<false, true><<<fusedBlocks, 512, 0, stream>>>(
        h1q, h1, ebufp, bcur, wb2l, wb2r, b2, nullptr, nullptr,
        wbm1, wbm2, bm1, bm2, out, N);
}